// Round 6
// baseline (266.482 us; speedup 1.0000x reference)
//
#include <hip/hip_runtime.h>
#include <hip/hip_bf16.h>

typedef __bf16 bf16x8_t __attribute__((ext_vector_type(8)));
typedef float f32x4_t __attribute__((ext_vector_type(4)));

#define SCALE_ZB 7.2134752044448169f   // 5 * log2(e): logits in log2 domain
#define LN2 0.69314718055994531f
#define E2(x) __builtin_amdgcn_exp2f(x)
#define LG2(x) __builtin_amdgcn_logf(x)

// ws byte offsets
#define WS_ACC   0u        // 5 floats used
#define WS_CNT   256u      // int[2048]
#define WS_BASE  8448u     // int[2048]
#define WS_CUR   16640u    // int[2048]
#define WS_PERM  24832u    // int[65536]          (ends 286976)
#define WS_ANC   294912u   // bf16[262144] 512KB  (ends 819200)
#define WS_PART  819200u   // float2[65536*4] 2MB (ends 2916352)
#define WS_ZERO  24832u
// acc: 0 posdot_raw, 1 zsq, 2 hsq, 3 l2se_sum, 4 cent_ssq_over_n

__device__ __forceinline__ void gload_lds16(const void* g, void* l) {
    __builtin_amdgcn_global_load_lds((const __attribute__((address_space(1))) unsigned int*)g,
                                     (__attribute__((address_space(3))) unsigned int*)l,
                                     16, 0, 0);
}

// ---- anchors f32 -> bf16 packed in MFMA B-fragment order + label histogram ----
// layout: [chunk c 0..127][kk 0..3][lane 0..63][e 0..7]
// lane=(g<<4)|l15 holds anchor (c*16+l15), k = kk*32 + g*8 + e
__global__ void prepHist(const float* __restrict__ anc, __bf16* __restrict__ out,
                         const int* __restrict__ labels, int* __restrict__ cnt) {
    int i = blockIdx.x * 256 + threadIdx.x;   // 0..65535
    atomicAdd(&cnt[labels[i]], 1);
    if (i < 32768) {
        int m = i >> 4, k0 = (i & 15) << 3;
        int kk = k0 >> 5, g = (k0 >> 3) & 3, l15 = m & 15, c = m >> 4;
        int lane = (g << 4) | l15;
        int base = (((c << 2) + kk) << 9) + (lane << 3);
        const float4* a4 = (const float4*)anc + (size_t)m * 32 + (k0 >> 2);
        float4 f0 = a4[0], f1 = a4[1];
        bf16x8_t pk;
        pk[0] = (__bf16)f0.x; pk[1] = (__bf16)f0.y; pk[2] = (__bf16)f0.z; pk[3] = (__bf16)f0.w;
        pk[4] = (__bf16)f1.x; pk[5] = (__bf16)f1.y; pk[6] = (__bf16)f1.z; pk[7] = (__bf16)f1.w;
        *(bf16x8_t*)&out[base] = pk;
    }
}

__global__ void scanK(const int* __restrict__ cnt, int* __restrict__ base,
                      int* __restrict__ cursor) {
    __shared__ int wsum[4];
    int t = threadIdx.x, lane = t & 63, w = t >> 6;
    int c[8], tot = 0;
    #pragma unroll
    for (int q = 0; q < 8; ++q) { c[q] = cnt[t * 8 + q]; tot += c[q]; }
    int sc = tot;
    #pragma unroll
    for (int off = 1; off < 64; off <<= 1) {
        int o = __shfl_up(sc, off);
        if (lane >= off) sc += o;
    }
    if (lane == 63) wsum[w] = sc;
    __syncthreads();
    int woff = 0;
    for (int ww = 0; ww < w; ++ww) woff += wsum[ww];
    int ex = woff + sc - tot;
    #pragma unroll
    for (int q = 0; q < 8; ++q) {
        base[t * 8 + q] = ex;
        cursor[t * 8 + q] = ex;
        ex += c[q];
    }
}

__global__ void scatK(const int* __restrict__ labels, int* __restrict__ cursor,
                      int* __restrict__ perm) {
    int i = blockIdx.x * 256 + threadIdx.x;
    int l = labels[i];
    int p = atomicAdd(&cursor[l], 1);
    perm[p] = i;
}

// WG = 8 waves (512 thr), 128 KB LDS = one M-quarter (512 anchors).
// bid = rb*4 + q : rb row-block (256 rows), q M-quarter. Wave w -> 32 rows.
// One barrier total; main loop is LDS+MFMA+VALU only.
__launch_bounds__(512)
__global__ void fusedM(const float* __restrict__ z,
                       const float* __restrict__ he,
                       const float* __restrict__ hc,
                       const float* __restrict__ ancf,
                       const int* __restrict__ labels,
                       const __bf16* __restrict__ ancb,
                       const int* __restrict__ cnt,
                       const int* __restrict__ basep,
                       const int* __restrict__ perm,
                       float* __restrict__ acc,
                       float2* __restrict__ part) {
    __shared__ __bf16 bsm[65536];   // 128 KB: [32 chunks][4 kk][64 lanes][8 bf16]

    const int tid  = threadIdx.x;
    const int lane = tid & 63;
    const int w    = tid >> 6;
    const int l15  = lane & 15, g = lane >> 4;
    const int rb   = blockIdx.x >> 2;
    const int q    = blockIdx.x & 3;
    const int R0   = (rb << 8) + (w << 5);

    // ---- stage quarter q of ancb -> LDS (issued first, lands under prologue) ----
    {
        const __bf16* src = ancb + (q << 16) + (w << 13);
        #pragma unroll
        for (int i = 0; i < 16; ++i)
            gload_lds16(src + (i << 9) + (lane << 3), &bsm[(w << 13) + (i << 9)]);
    }

    // ---- h-align slice (grid-stride float4; 4.19M float4 per array / 524288 thr) ----
    float hp = 0.f;
    {
        int gt = (blockIdx.x << 9) + tid;
        const float4* hev = (const float4*)he;
        const float4* hcv = (const float4*)hc;
        #pragma unroll 4
        for (int i = 0; i < 8; ++i) {
            float4 e = hev[(size_t)i * 524288 + gt];
            float4 c = hcv[(size_t)i * 524288 + gt];
            float dx = e.x - c.x, dy = e.y - c.y, dz = e.z - c.z, dw = e.w - c.w;
            hp += dx * dx + dy * dy + dz * dz + dw * dw;
        }
    }

    // ---- A-fragments from z; q0 computes pos-dot, q1 computes zsq ----
    bf16x8_t Af[2][4];
    float sp = 0.f;
    #pragma unroll
    for (int rf = 0; rf < 2; ++rf) {
        int row = R0 + (rf << 4) + l15;
        const float4* zr = (const float4*)z + ((size_t)row << 5);
        const float4* ar;
        if (q == 0) {
            int lb = labels[row];
            ar = (const float4*)ancf + ((size_t)lb << 5);
        }
        #pragma unroll
        for (int kk = 0; kk < 4; ++kk) {
            int qq = (kk << 3) + (g << 1);
            float4 z0 = zr[qq], z1 = zr[qq + 1];
            if (q == 0) {
                float4 a0 = ar[qq], a1 = ar[qq + 1];
                sp += z0.x*a0.x + z0.y*a0.y + z0.z*a0.z + z0.w*a0.w
                    + z1.x*a1.x + z1.y*a1.y + z1.z*a1.z + z1.w*a1.w;
            } else if (q == 1) {
                sp += z0.x*z0.x + z0.y*z0.y + z0.z*z0.z + z0.w*z0.w
                    + z1.x*z1.x + z1.y*z1.y + z1.z*z1.z + z1.w*z1.w;
            }
            bf16x8_t pk;
            pk[0] = (__bf16)(z0.x * SCALE_ZB); pk[1] = (__bf16)(z0.y * SCALE_ZB);
            pk[2] = (__bf16)(z0.z * SCALE_ZB); pk[3] = (__bf16)(z0.w * SCALE_ZB);
            pk[4] = (__bf16)(z1.x * SCALE_ZB); pk[5] = (__bf16)(z1.y * SCALE_ZB);
            pk[6] = (__bf16)(z1.z * SCALE_ZB); pk[7] = (__bf16)(z1.w * SCALE_ZB);
            Af[rf][kk] = pk;
        }
    }

    // scalar partials -> atomics
    #pragma unroll
    for (int off = 32; off; off >>= 1) {
        sp += __shfl_xor(sp, off);
        hp += __shfl_xor(hp, off);
    }
    if (lane == 0) {
        atomicAdd(&acc[2], hp);
        if (q < 2) atomicAdd(q == 0 ? &acc[0] : &acc[1], sp);
    }

    asm volatile("s_waitcnt vmcnt(0)" ::: "memory");
    __syncthreads();   // LDS quarter resident; the ONLY barrier

    // ---- main loop: 32 chunks (this quarter), LDS-only, no barriers ----
    float m0[4], s0[4], m1[4], s1[4];
    #pragma unroll
    for (int r = 0; r < 4; ++r) { m0[r] = -1.0e30f; s0[r] = 0.f; m1[r] = -1.0e30f; s1[r] = 0.f; }

    for (int c = 0; c < 32; c += 2) {
        bf16x8_t B0[4], B1[4];
        #pragma unroll
        for (int kk = 0; kk < 4; ++kk) {
            B0[kk] = *(const bf16x8_t*)&bsm[(((c << 2) | kk) << 9) + (lane << 3)];
            B1[kk] = *(const bf16x8_t*)&bsm[((((c + 1) << 2) | kk) << 9) + (lane << 3)];
        }
        f32x4_t aA = {0.f,0.f,0.f,0.f}, aB = {0.f,0.f,0.f,0.f};
        f32x4_t bA = {0.f,0.f,0.f,0.f}, bB = {0.f,0.f,0.f,0.f};
        #pragma unroll
        for (int kk = 0; kk < 4; ++kk) {
            aA = __builtin_amdgcn_mfma_f32_16x16x32_bf16(Af[0][kk], B0[kk], aA, 0, 0, 0);
            aB = __builtin_amdgcn_mfma_f32_16x16x32_bf16(Af[1][kk], B0[kk], aB, 0, 0, 0);
        }
        #pragma unroll
        for (int kk = 0; kk < 4; ++kk) {
            bA = __builtin_amdgcn_mfma_f32_16x16x32_bf16(Af[0][kk], B1[kk], bA, 0, 0, 0);
            bB = __builtin_amdgcn_mfma_f32_16x16x32_bf16(Af[1][kk], B1[kk], bB, 0, 0, 0);
        }
        // batched-2 online-LSE: 3 exp2 per 2 logits
        #pragma unroll
        for (int r = 0; r < 4; ++r) {
            {
                float v0 = aA[r], v1 = bA[r];
                float nm = fmaxf(fmaxf(v0, v1), m0[r]);
                s0[r] = s0[r] * E2(m0[r] - nm) + E2(v0 - nm) + E2(v1 - nm);
                m0[r] = nm;
            }
            {
                float v0 = aB[r], v1 = bB[r];
                float nm = fmaxf(fmaxf(v0, v1), m1[r]);
                s1[r] = s1[r] * E2(m1[r] - nm) + E2(v0 - nm) + E2(v1 - nm);
                m1[r] = nm;
            }
        }
    }

    // ---- merge (m,s) across the 16 anchor-lanes; write per-row quarter partials ----
    #pragma unroll
    for (int r = 0; r < 4; ++r) {
        #pragma unroll
        for (int off = 1; off < 16; off <<= 1) {
            float om = __shfl_xor(m0[r], off), os = __shfl_xor(s0[r], off);
            float nm = fmaxf(m0[r], om);
            s0[r] = s0[r] * E2(m0[r] - nm) + os * E2(om - nm);
            m0[r] = nm;
            om = __shfl_xor(m1[r], off); os = __shfl_xor(s1[r], off);
            nm = fmaxf(m1[r], om);
            s1[r] = s1[r] * E2(m1[r] - nm) + os * E2(om - nm);
            m1[r] = nm;
        }
    }
    if (l15 == 0) {
        #pragma unroll
        for (int r = 0; r < 4; ++r) {
            int row0 = R0 + (g << 2) + r;
            part[((row0) << 2) + q]      = make_float2(m0[r], s0[r]);
            part[((row0 + 16) << 2) + q] = make_float2(m1[r], s1[r]);
        }
    }

    // ---- centroid tail: one wave per label (gw<2048), overlaps other WGs' loops ----
    int gw = (blockIdx.x << 3) + w;
    if (gw < 2048) {
        const int n = cnt[gw], bs = basep[gw];
        float ax = 0.f, ay = 0.f;
        const float2* z2 = (const float2*)z;
        for (int e0 = 0; e0 < n; e0 += 64) {
            int pe = (e0 + lane < n) ? perm[bs + e0 + lane] : 0;
            int c2 = n - e0; if (c2 > 64) c2 = 64;
            int j = 0;
            for (; j + 3 < c2; j += 4) {
                int r0 = __shfl(pe, j), r1 = __shfl(pe, j + 1);
                int r2 = __shfl(pe, j + 2), r3 = __shfl(pe, j + 3);
                float2 v0 = z2[((size_t)r0 << 6) + lane];
                float2 v1 = z2[((size_t)r1 << 6) + lane];
                float2 v2 = z2[((size_t)r2 << 6) + lane];
                float2 v3 = z2[((size_t)r3 << 6) + lane];
                ax += v0.x + v1.x + v2.x + v3.x;
                ay += v0.y + v1.y + v2.y + v3.y;
            }
            for (; j < c2; ++j) {
                int r0 = __shfl(pe, j);
                float2 v0 = z2[((size_t)r0 << 6) + lane];
                ax += v0.x; ay += v0.y;
            }
        }
        float ssq = ax * ax + ay * ay;
        #pragma unroll
        for (int off = 32; off; off >>= 1) ssq += __shfl_xor(ssq, off);
        if (lane == 0) atomicAdd(&acc[4], ssq / fmaxf((float)n, 1.f));
    }
}

// ---- merge the four M-quarter partials per row, LSE, sum ----
__global__ void mergeL(const float4* __restrict__ part4, float* __restrict__ acc) {
    int t = blockIdx.x * 256 + threadIdx.x;   // 0..65535 rows
    float4 A = part4[t << 1], Bq = part4[(t << 1) + 1];   // (m0,s0,m1,s1),(m2,s2,m3,s3)
    float nm = fmaxf(fmaxf(A.x, A.z), fmaxf(Bq.x, Bq.z));
    float s = A.y * E2(A.x - nm) + A.w * E2(A.z - nm)
            + Bq.y * E2(Bq.x - nm) + Bq.w * E2(Bq.z - nm);
    float lse = nm + LG2(s);
    #pragma unroll
    for (int off = 32; off; off >>= 1) lse += __shfl_xor(lse, off);
    if ((threadIdx.x & 63) == 0) atomicAdd(&acc[3], lse);
}

__global__ void finalize(const float* __restrict__ acc, float* __restrict__ out) {
    float lc   = (LN2 * acc[3] - 5.0f * acc[0]) * (1.0f / 65536.0f);
    float cent = (acc[1] - acc[4]) * (1.0f / 8388608.0f);
    float hal  = acc[2] * (1.0f / 16777216.0f);
    out[0] = lc + 0.05f * cent + 0.1f * hal;
}

extern "C" void kernel_launch(void* const* d_in, const int* in_sizes, int n_in,
                              void* d_out, int out_size, void* d_ws, size_t ws_size,
                              hipStream_t stream) {
    const float* z      = (const float*)d_in[0];
    const float* he     = (const float*)d_in[1];
    const float* hc     = (const float*)d_in[2];
    const float* anc    = (const float*)d_in[3];
    const int*   labels = (const int*)d_in[4];

    char* ws = (char*)d_ws;
    float*  acc    = (float*)(ws + WS_ACC);
    int*    cnt    = (int*)(ws + WS_CNT);
    int*    basep  = (int*)(ws + WS_BASE);
    int*    cursor = (int*)(ws + WS_CUR);
    int*    perm   = (int*)(ws + WS_PERM);
    __bf16* ancb   = (__bf16*)(ws + WS_ANC);
    float2* part   = (float2*)(ws + WS_PART);

    hipMemsetAsync(d_ws, 0, WS_ZERO, stream);
    prepHist<<<256, 256, 0, stream>>>(anc, ancb, labels, cnt);
    scanK<<<1, 256, 0, stream>>>(cnt, basep, cursor);
    scatK<<<256, 256, 0, stream>>>(labels, cursor, perm);
    fusedM<<<1024, 512, 0, stream>>>(z, he, hc, anc, labels, ancb, cnt, basep, perm, acc, part);
    mergeL<<<256, 256, 0, stream>>>((const float4*)part, acc);
    finalize<<<1, 1, 0, stream>>>(acc, (float*)d_out);
}

// Round 8
// 234.382 us; speedup vs baseline: 1.1370x; 1.1370x over previous
//
#include <hip/hip_runtime.h>
#include <hip/hip_bf16.h>

typedef __bf16 bf16x8_t __attribute__((ext_vector_type(8)));
typedef float f32x4_t __attribute__((ext_vector_type(4)));

#define SCALE_ZB 7.2134752044448169f   // 5 * log2(e): logits in log2 domain
#define LN2 0.69314718055994531f
#define E2(x) __builtin_amdgcn_exp2f(x)
#define LG2(x) __builtin_amdgcn_logf(x)

// ws byte offsets
#define WS_ACC   0u        // 5 floats used
#define WS_CNT   256u      // int[2048]
#define WS_BASE  8448u     // int[2048]
#define WS_CUR   16640u    // int[2048]
#define WS_PERM  24832u    // int[65536]
#define WS_ANC   294912u   // bf16[262144] in B-fragment order (512 KB)
#define WS_ZERO  8448u     // zero acc + cnt only
// acc: 0 posdot_raw, 1 zsq, 2 hsq, 3 l2se_sum, 4 cent_ssq_over_n

// ---- anchors f32 -> bf16 packed in MFMA B-fragment order + label histogram ----
// layout: [chunk c 0..127][kk 0..3][lane 0..63][e 0..7]
// lane=(g<<4)|l15 holds anchor (c*16+l15), k = kk*32 + g*8 + e
__global__ void prepHist(const float* __restrict__ anc, __bf16* __restrict__ out,
                         const int* __restrict__ labels, int* __restrict__ cnt) {
    int i = blockIdx.x * 256 + threadIdx.x;   // 0..65535
    atomicAdd(&cnt[labels[i]], 1);
    if (i < 32768) {
        int m = i >> 4, k0 = (i & 15) << 3;
        int kk = k0 >> 5, g = (k0 >> 3) & 3, l15 = m & 15, c = m >> 4;
        int lane = (g << 4) | l15;
        int base = (((c << 2) + kk) << 9) + (lane << 3);
        const float4* a4 = (const float4*)anc + (size_t)m * 32 + (k0 >> 2);
        float4 f0 = a4[0], f1 = a4[1];
        bf16x8_t pk;
        pk[0] = (__bf16)f0.x; pk[1] = (__bf16)f0.y; pk[2] = (__bf16)f0.z; pk[3] = (__bf16)f0.w;
        pk[4] = (__bf16)f1.x; pk[5] = (__bf16)f1.y; pk[6] = (__bf16)f1.z; pk[7] = (__bf16)f1.w;
        *(bf16x8_t*)&out[base] = pk;
    }
}

__global__ void scanK(const int* __restrict__ cnt, int* __restrict__ base,
                      int* __restrict__ cursor) {
    __shared__ int wsum[4];
    int t = threadIdx.x, lane = t & 63, w = t >> 6;
    int c[8], tot = 0;
    #pragma unroll
    for (int q = 0; q < 8; ++q) { c[q] = cnt[t * 8 + q]; tot += c[q]; }
    int sc = tot;
    #pragma unroll
    for (int off = 1; off < 64; off <<= 1) {
        int o = __shfl_up(sc, off);
        if (lane >= off) sc += o;
    }
    if (lane == 63) wsum[w] = sc;
    __syncthreads();
    int woff = 0;
    for (int ww = 0; ww < w; ++ww) woff += wsum[ww];
    int ex = woff + sc - tot;
    #pragma unroll
    for (int q = 0; q < 8; ++q) {
        base[t * 8 + q] = ex;
        cursor[t * 8 + q] = ex;
        ex += c[q];
    }
}

__global__ void scatK(const int* __restrict__ labels, int* __restrict__ cursor,
                      int* __restrict__ perm) {
    int i = blockIdx.x * 256 + threadIdx.x;
    int l = labels[i];
    int p = atomicAdd(&cursor[l], 1);
    perm[p] = i;
}

// Heterogeneous kernel:
//   blocks [0,512):    GEMM+LSE role (4 waves x 32 rows, no LDS, no barriers)
//   blocks [512,2048): h-align streaming role; first 256 of them also do centroid
__launch_bounds__(256)
__global__ void megaK(const float* __restrict__ z,
                      const float* __restrict__ he,
                      const float* __restrict__ hc,
                      const float* __restrict__ ancf,
                      const int* __restrict__ labels,
                      const __bf16* __restrict__ ancb,
                      const int* __restrict__ cnt,
                      const int* __restrict__ basep,
                      const int* __restrict__ perm,
                      float* __restrict__ acc) {
    const int tid  = threadIdx.x;
    const int lane = tid & 63;
    const int w    = tid >> 6;
    const int bid  = blockIdx.x;

    if (bid < 512) {
        // ================= GEMM + LSE role =================
        const int l15 = lane & 15, g = lane >> 4;
        const int gw  = (bid << 2) + w;     // 0..2047
        const int R0  = gw << 5;            // 32 rows per wave

        // ---- A-fragments from z + pos-dot + zsq ----
        bf16x8_t Af[2][4];
        float posp = 0.f, zsqp = 0.f;
        #pragma unroll
        for (int rf = 0; rf < 2; ++rf) {
            int row = R0 + (rf << 4) + l15;
            int lb = labels[row];
            const float4* zr = (const float4*)z + ((size_t)row << 5);
            const float4* ar = (const float4*)ancf + ((size_t)lb << 5);
            #pragma unroll
            for (int kk = 0; kk < 4; ++kk) {
                int qq = (kk << 3) + (g << 1);
                float4 z0 = zr[qq], z1 = zr[qq + 1];
                float4 a0 = ar[qq], a1 = ar[qq + 1];
                posp += z0.x*a0.x + z0.y*a0.y + z0.z*a0.z + z0.w*a0.w
                      + z1.x*a1.x + z1.y*a1.y + z1.z*a1.z + z1.w*a1.w;
                zsqp += z0.x*z0.x + z0.y*z0.y + z0.z*z0.z + z0.w*z0.w
                      + z1.x*z1.x + z1.y*z1.y + z1.z*z1.z + z1.w*z1.w;
                bf16x8_t pk;
                pk[0] = (__bf16)(z0.x * SCALE_ZB); pk[1] = (__bf16)(z0.y * SCALE_ZB);
                pk[2] = (__bf16)(z0.z * SCALE_ZB); pk[3] = (__bf16)(z0.w * SCALE_ZB);
                pk[4] = (__bf16)(z1.x * SCALE_ZB); pk[5] = (__bf16)(z1.y * SCALE_ZB);
                pk[6] = (__bf16)(z1.z * SCALE_ZB); pk[7] = (__bf16)(z1.w * SCALE_ZB);
                Af[rf][kk] = pk;
            }
        }
        #pragma unroll
        for (int off = 32; off; off >>= 1) {
            posp += __shfl_xor(posp, off);
            zsqp += __shfl_xor(zsqp, off);
        }
        if (lane == 0) {
            atomicAdd(&acc[0], posp);
            atomicAdd(&acc[1], zsqp);
        }

        // ---- main loop: 128 chunks, 4-deep rotation, per-row batched-2 LSE ----
        float m0[4], s0[4], m1[4], s1[4];
        #pragma unroll
        for (int r = 0; r < 4; ++r) { m0[r] = -1.0e30f; s0[r] = 0.f; m1[r] = -1.0e30f; s1[r] = 0.f; }

        const bf16x8_t* Bp = (const bf16x8_t*)ancb;

#define LOADB(Bx, cc) { _Pragma("unroll") \
        for (int kk = 0; kk < 4; ++kk) Bx[kk] = Bp[((((cc) << 2) | kk) << 6) + lane]; }

#define CHUNK2(Bx, By) { \
        f32x4_t aA0 = {0.f,0.f,0.f,0.f}, aB0 = {0.f,0.f,0.f,0.f}; \
        f32x4_t aA1 = {0.f,0.f,0.f,0.f}, aB1 = {0.f,0.f,0.f,0.f}; \
        _Pragma("unroll") \
        for (int kk = 0; kk < 4; ++kk) { \
            aA0 = __builtin_amdgcn_mfma_f32_16x16x32_bf16(Af[0][kk], Bx[kk], aA0, 0, 0, 0); \
            aB0 = __builtin_amdgcn_mfma_f32_16x16x32_bf16(Af[1][kk], Bx[kk], aB0, 0, 0, 0); \
        } \
        _Pragma("unroll") \
        for (int kk = 0; kk < 4; ++kk) { \
            aA1 = __builtin_amdgcn_mfma_f32_16x16x32_bf16(Af[0][kk], By[kk], aA1, 0, 0, 0); \
            aB1 = __builtin_amdgcn_mfma_f32_16x16x32_bf16(Af[1][kk], By[kk], aB1, 0, 0, 0); \
        } \
        _Pragma("unroll") \
        for (int r = 0; r < 4; ++r) { \
            { \
                float v0 = aA0[r], v1 = aA1[r]; \
                float nm = fmaxf(fmaxf(v0, v1), m0[r]); \
                s0[r] = s0[r] * E2(m0[r] - nm) + E2(v0 - nm) + E2(v1 - nm); \
                m0[r] = nm; \
            } \
            { \
                float v0 = aB0[r], v1 = aB1[r]; \
                float nm = fmaxf(fmaxf(v0, v1), m1[r]); \
                s1[r] = s1[r] * E2(m1[r] - nm) + E2(v0 - nm) + E2(v1 - nm); \
                m1[r] = nm; \
            } \
        } }

        bf16x8_t Ba[4], Bb[4], Bc[4], Bd[4];
        LOADB(Ba, 0) LOADB(Bb, 1) LOADB(Bc, 2) LOADB(Bd, 3)

        for (int c = 0; c < 128; c += 4) {
            CHUNK2(Ba, Bb)
            if (c < 124) { LOADB(Ba, c + 4) LOADB(Bb, c + 5) }
            CHUNK2(Bc, Bd)
            if (c < 124) { LOADB(Bc, c + 6) LOADB(Bd, c + 7) }
        }
#undef LOADB
#undef CHUNK2

        // ---- merge (m,s) across the 16 anchor-lanes ----
        #pragma unroll
        for (int r = 0; r < 4; ++r) {
            #pragma unroll
            for (int off = 1; off < 16; off <<= 1) {
                float om = __shfl_xor(m0[r], off), os = __shfl_xor(s0[r], off);
                float nm = fmaxf(m0[r], om);
                s0[r] = s0[r] * E2(m0[r] - nm) + os * E2(om - nm);
                m0[r] = nm;
                om = __shfl_xor(m1[r], off); os = __shfl_xor(s1[r], off);
                nm = fmaxf(m1[r], om);
                s1[r] = s1[r] * E2(m1[r] - nm) + os * E2(om - nm);
                m1[r] = nm;
            }
        }
        float lsum = 0.f;
        #pragma unroll
        for (int r = 0; r < 4; ++r)
            lsum += (m0[r] + LG2(s0[r])) + (m1[r] + LG2(s1[r]));
        #pragma unroll
        for (int off = 32; off; off >>= 1) lsum += __shfl_xor(lsum, off);
        if (lane == 0) atomicAdd(&acc[3], lsum * 0.0625f);   // /16 l15 duplication

    } else {
        // ================= h-align streaming role =================
        const int hb = bid - 512;              // 0..1535
        int gt = (hb << 8) + tid;              // 0..393215
        const float4* hev = (const float4*)he;
        const float4* hcv = (const float4*)hc;
        float hp = 0.f;
        int i = gt;
        #pragma unroll 5
        for (int it = 0; it < 10; ++it, i += 393216) {
            float4 e = hev[i];
            float4 c = hcv[i];
            float dx = e.x - c.x, dy = e.y - c.y, dz = e.z - c.z, dw = e.w - c.w;
            hp += dx * dx + dy * dy + dz * dz + dw * dw;
        }
        if (i < 4194304) {
            float4 e = hev[i];
            float4 c = hcv[i];
            float dx = e.x - c.x, dy = e.y - c.y, dz = e.z - c.z, dw = e.w - c.w;
            hp += dx * dx + dy * dy + dz * dz + dw * dw;
        }
        #pragma unroll
        for (int off = 32; off; off >>= 1) hp += __shfl_xor(hp, off);
        if (lane == 0) atomicAdd(&acc[2], hp);

        // ---- centroid sub-role: blocks 512..767, 2 labels per wave ----
        if (hb < 256) {
            const float2* z2 = (const float2*)z;
            #pragma unroll
            for (int li = 0; li < 2; ++li) {
                int lb = (hb << 3) + (w << 1) + li;
                int n = cnt[lb], bs = basep[lb];
                float ax = 0.f, ay = 0.f;
                for (int e0 = 0; e0 < n; e0 += 64) {
                    int pe = (e0 + lane < n) ? perm[bs + e0 + lane] : 0;
                    int c2 = n - e0; if (c2 > 64) c2 = 64;
                    int j = 0;
                    for (; j + 3 < c2; j += 4) {
                        int r0 = __shfl(pe, j), r1 = __shfl(pe, j + 1);
                        int r2 = __shfl(pe, j + 2), r3 = __shfl(pe, j + 3);
                        float2 v0 = z2[((size_t)r0 << 6) + lane];
                        float2 v1 = z2[((size_t)r1 << 6) + lane];
                        float2 v2 = z2[((size_t)r2 << 6) + lane];
                        float2 v3 = z2[((size_t)r3 << 6) + lane];
                        ax += v0.x + v1.x + v2.x + v3.x;
                        ay += v0.y + v1.y + v2.y + v3.y;
                    }
                    for (; j < c2; ++j) {
                        int r0 = __shfl(pe, j);
                        float2 v0 = z2[((size_t)r0 << 6) + lane];
                        ax += v0.x; ay += v0.y;
                    }
                }
                float ssq = ax * ax + ay * ay;
                #pragma unroll
                for (int off = 32; off; off >>= 1) ssq += __shfl_xor(ssq, off);
                if (lane == 0) atomicAdd(&acc[4], ssq / fmaxf((float)n, 1.f));
            }
        }
    }
}

__global__ void finalize(const float* __restrict__ acc, float* __restrict__ out) {
    float lc   = (LN2 * acc[3] - 5.0f * acc[0]) * (1.0f / 65536.0f);
    float cent = (acc[1] - acc[4]) * (1.0f / 8388608.0f);
    float hal  = acc[2] * (1.0f / 16777216.0f);
    out[0] = lc + 0.05f * cent + 0.1f * hal;
}

extern "C" void kernel_launch(void* const* d_in, const int* in_sizes, int n_in,
                              void* d_out, int out_size, void* d_ws, size_t ws_size,
                              hipStream_t stream) {
    const float* z      = (const float*)d_in[0];
    const float* he     = (const float*)d_in[1];
    const float* hc     = (const float*)d_in[2];
    const float* anc    = (const float*)d_in[3];
    const int*   labels = (const int*)d_in[4];

    char* ws = (char*)d_ws;
    float*  acc    = (float*)(ws + WS_ACC);
    int*    cnt    = (int*)(ws + WS_CNT);
    int*    basep  = (int*)(ws + WS_BASE);
    int*    cursor = (int*)(ws + WS_CUR);
    int*    perm   = (int*)(ws + WS_PERM);
    __bf16* ancb   = (__bf16*)(ws + WS_ANC);

    hipMemsetAsync(d_ws, 0, WS_ZERO, stream);
    prepHist<<<256, 256, 0, stream>>>(anc, ancb, labels, cnt);
    scanK<<<1, 256, 0, stream>>>(cnt, basep, cursor);
    scatK<<<256, 256, 0, stream>>>(labels, cursor, perm);
    megaK<<<2048, 256, 0, stream>>>(z, he, hc, anc, labels, ancb, cnt, basep, perm, acc);
    finalize<<<1, 1, 0, stream>>>(acc, (float*)d_out);
}